// Round 1
// baseline (1957.827 us; speedup 1.0000x reference)
//
#include <hip/hip_runtime.h>
#include <cstdint>
#include <cstddef>

// ---------------------------------------------------------------------------
// ActorNetSpiking: 3x conv1d(stride2,k5,C5) + 4x FC, LIF neurons, T=50, B=4096
// Strategy: layer-by-layer over full time axis; spike trains packed to bits
// via __ballot; FC layers as f32 VALU GEMM over M=(b,t)=204800 rows.
// ---------------------------------------------------------------------------

#define NB 4096
#define NT_STEPS 50

__device__ __forceinline__ void neuron_update(float syn, float& u, float& v, float& s) {
    u = u * 0.5f + syn;
    v = v * 0.75f * (1.0f - s) + u;
    s = (v > 0.5f) ? 1.0f : 0.0f;
}

// ------------------------- conv1: (B,1,360) -> (B,5,178) --------------------
// one block per b; 192 threads (3 waves), thread = output position j.
// input staged to LDS in two t-halves. Output spike bits: S1[b][t][o][3 u64],
// bit l (=j) of the 192-bit word group.
__global__ __launch_bounds__(192) void conv1_kernel(
    const float* __restrict__ x,        // (B,1,360,50)
    const float* __restrict__ w1,       // (5,1,5)
    const float* __restrict__ b1,       // (5,)
    unsigned long long* __restrict__ S1)
{
    __shared__ float xl[9000];          // 360 x 25
    const int tid = threadIdx.x;
    const int b = blockIdx.x;
    const int j = tid;
    const int lbase = (j < 178) ? 2 * j : 354;   // clamp inactive lanes in-bounds

    float wr[25], br[5];
#pragma unroll
    for (int q = 0; q < 25; ++q) wr[q] = w1[q];
#pragma unroll
    for (int o = 0; o < 5; ++o) br[o] = b1[o];

    float u[5], v[5], s[5];
#pragma unroll
    for (int o = 0; o < 5; ++o) { u[o] = 0.f; v[o] = 0.f; s[o] = 0.f; }

    const float* xb = x + (size_t)b * 18000;
    for (int half = 0; half < 2; ++half) {
        const int t0 = half * 25;
        __syncthreads();
        for (int e = tid; e < 9000; e += 192)
            xl[e] = xb[(e / 25) * 50 + t0 + (e % 25)];
        __syncthreads();
        for (int dt = 0; dt < 25; ++dt) {
            const int t = t0 + dt;
            float xv[5];
#pragma unroll
            for (int k = 0; k < 5; ++k) xv[k] = xl[(lbase + k) * 25 + dt];
#pragma unroll
            for (int o = 0; o < 5; ++o) {
                float syn = 0.f;
#pragma unroll
                for (int k = 0; k < 5; ++k) syn += wr[o * 5 + k] * xv[k];
                syn += br[o];
                neuron_update(syn, u[o], v[o], s[o]);
                unsigned long long m = __ballot(j < 178 && s[o] > 0.5f);
                if ((tid & 63) == 0)
                    S1[(((size_t)b * 50 + t) * 5 + o) * 3 + (tid >> 6)] = m;
            }
        }
    }
}

// ------------------------- conv2: (B,5,178) -> (B,5,87) ---------------------
// one block per b; 128 threads, thread = j2 (87 active). S1 read as u32 words.
// Output S2[b][t][o][3 u32] (87 bits).
__global__ __launch_bounds__(128) void conv2_kernel(
    const unsigned int* __restrict__ S1,   // [B][50][5][6] u32
    const float* __restrict__ w2,          // (5,5,5)
    const float* __restrict__ b2,
    unsigned int* __restrict__ S2)         // [B][50][5][3] u32
{
    __shared__ unsigned int s1l[1501];
    const int tid = threadIdx.x;
    const int b = blockIdx.x;

    float wr[125], br[5];
#pragma unroll
    for (int q = 0; q < 125; ++q) wr[q] = w2[q];
#pragma unroll
    for (int o = 0; o < 5; ++o) br[o] = b2[o];

    const unsigned int* src = S1 + (size_t)b * 1500;
    for (int e = tid; e < 1500; e += 128) s1l[e] = src[e];
    __syncthreads();

    const int p = (tid < 87) ? 2 * tid : 172;
    const int pw = p >> 5, ps = p & 31;

    float u[5], v[5], s[5];
#pragma unroll
    for (int o = 0; o < 5; ++o) { u[o] = 0.f; v[o] = 0.f; s[o] = 0.f; }

    for (int t = 0; t < 50; ++t) {
        float xv[25];
#pragma unroll
        for (int ci = 0; ci < 5; ++ci) {
            const int base = (t * 5 + ci) * 6 + pw;
            unsigned long long bits =
                ((((unsigned long long)s1l[base + 1]) << 32) | (unsigned long long)s1l[base]) >> ps;
#pragma unroll
            for (int k = 0; k < 5; ++k)
                xv[ci * 5 + k] = ((bits >> k) & 1ULL) ? 1.0f : 0.0f;
        }
#pragma unroll
        for (int o = 0; o < 5; ++o) {
            float syn = 0.f;
#pragma unroll
            for (int q = 0; q < 25; ++q) syn += wr[o * 25 + q] * xv[q];
            syn += br[o];
            neuron_update(syn, u[o], v[o], s[o]);
            unsigned long long m = __ballot(tid < 87 && s[o] > 0.5f);
            const size_t outb = (((size_t)b * 50 + t) * 5 + o) * 3;
            if (tid == 0) {
                S2[outb]     = (unsigned int)m;
                S2[outb + 1] = (unsigned int)(m >> 32);
            }
            if (tid == 64) S2[outb + 2] = (unsigned int)m;
        }
    }
}

// ------------------------- conv3: (B,5,87) -> (B,5,42) ----------------------
// one block per b; 64 threads, thread = j3 (42 active).
// Output S3[b][t][o][2 u32] (42 bits).
__global__ __launch_bounds__(64) void conv3_kernel(
    const unsigned int* __restrict__ S2,   // [B][50][5][3] u32
    const float* __restrict__ w3,
    const float* __restrict__ b3,
    unsigned int* __restrict__ S3)         // [B][50][5][2] u32
{
    __shared__ unsigned int s2l[751];
    const int tid = threadIdx.x;
    const int b = blockIdx.x;

    float wr[125], br[5];
#pragma unroll
    for (int q = 0; q < 125; ++q) wr[q] = w3[q];
#pragma unroll
    for (int o = 0; o < 5; ++o) br[o] = b3[o];

    const unsigned int* src = S2 + (size_t)b * 750;
    for (int e = tid; e < 750; e += 64) s2l[e] = src[e];
    __syncthreads();

    const int p = (tid < 42) ? 2 * tid : 82;
    const int pw = p >> 5, ps = p & 31;

    float u[5], v[5], s[5];
#pragma unroll
    for (int o = 0; o < 5; ++o) { u[o] = 0.f; v[o] = 0.f; s[o] = 0.f; }

    for (int t = 0; t < 50; ++t) {
        float xv[25];
#pragma unroll
        for (int ci = 0; ci < 5; ++ci) {
            const int base = (t * 5 + ci) * 3 + pw;
            unsigned long long bits =
                ((((unsigned long long)s2l[base + 1]) << 32) | (unsigned long long)s2l[base]) >> ps;
#pragma unroll
            for (int k = 0; k < 5; ++k)
                xv[ci * 5 + k] = ((bits >> k) & 1ULL) ? 1.0f : 0.0f;
        }
#pragma unroll
        for (int o = 0; o < 5; ++o) {
            float syn = 0.f;
#pragma unroll
            for (int q = 0; q < 25; ++q) syn += wr[o * 25 + q] * xv[q];
            syn += br[o];
            neuron_update(syn, u[o], v[o], s[o]);
            unsigned long long m = __ballot(tid < 42 && s[o] > 0.5f);
            if (tid == 0) {
                const size_t outb = (((size_t)b * 50 + t) * 5 + o) * 2;
                S3[outb]     = (unsigned int)m;
                S3[outb + 1] = (unsigned int)(m >> 32);
            }
        }
    }
}

// ------------------------- FC GEMM: syn = spikes @ W^T ----------------------
// M = chunk*50 rows (b-major, t-minor), N = NT, K tiled by 32.
// Block 256 threads, tile 128(M) x NT(N); thread computes 8m x (NT/16)n.
// A staged from bit rows (FIRST: S3 format 10 u32 + normal_spikes; else 8 u32).
template <int KT, int NT, bool FIRST>
__global__ __launch_bounds__(256) void fc_gemm_kernel(
    const unsigned int* __restrict__ bits,
    const float* __restrict__ normal,      // (B,6,50), FIRST only
    const float* __restrict__ W,           // (N, KREAL) row-major
    const float* __restrict__ bias,        // (N,)
    float* __restrict__ syn,               // [chunk*50][NT]
    int b0)
{
    constexpr int KREAL = FIRST ? 216 : 256;
    constexpr int WPR   = FIRST ? 10 : 8;
    constexpr int NR    = NT / 16;
    constexpr int BS    = NT + 4;

    __shared__ __align__(16) float a_lds[32 * 128];
    __shared__ __align__(16) float b_lds[32 * BS];

    const int tid = threadIdx.x;
    const int m0 = blockIdx.x * 128;
    const int tm = tid & 15, tn = tid >> 4;

    // A-staging coords: thread covers row ml, k-range [kg, kg+16)
    const int ml = tid >> 1;
    const int kg = (tid & 1) * 16;
    const int rowG = b0 * 50 + (m0 + ml);
    const unsigned int* rowA = bits + (size_t)rowG * WPR;
    const int bA = rowG / 50, tA = rowG % 50;

    // B-staging coords
    const int klB = tid & 31, nl0 = tid >> 5;

    float acc[8][NR];
#pragma unroll
    for (int i = 0; i < 8; ++i)
#pragma unroll
        for (int r = 0; r < NR; ++r) acc[i][r] = 0.f;

    for (int kt = 0; kt < KT; ++kt) {
        const int k0 = kt * 32;
        // ---- stage A (expand bits -> f32) ----
        float av[16];
        if (FIRST) {
#pragma unroll
            for (int i = 0; i < 16; ++i) {
                const int k = k0 + kg + i;
                float val = 0.f;
                if (k < 210) {
                    const int o = k / 42, jj = k - o * 42;
                    val = ((rowA[o * 2 + (jj >> 5)] >> (jj & 31)) & 1u) ? 1.f : 0.f;
                } else if (k < 216) {
                    val = normal[((size_t)bA * 6 + (k - 210)) * 50 + tA];
                }
                av[i] = val;
            }
        } else {
            const unsigned int wrd = rowA[kt];
#pragma unroll
            for (int i = 0; i < 16; ++i)
                av[i] = ((wrd >> (kg + i)) & 1u) ? 1.f : 0.f;
        }
#pragma unroll
        for (int i = 0; i < 16; ++i) a_lds[(kg + i) * 128 + ml] = av[i];

        // ---- stage B ----
        {
            const int k = k0 + klB;
#pragma unroll
            for (int nn = 0; nn < NT / 8; ++nn) {
                const int nl = nl0 + nn * 8;
                float wv = 0.f;
                if (k < KREAL) wv = W[(size_t)nl * KREAL + k];
                b_lds[klB * BS + nl] = wv;
            }
        }
        __syncthreads();

        // ---- inner product ----
#pragma unroll
        for (int kk = 0; kk < 32; ++kk) {
            float a[8];
            const float4 a0 = *reinterpret_cast<const float4*>(&a_lds[kk * 128 + tm * 8]);
            const float4 a1 = *reinterpret_cast<const float4*>(&a_lds[kk * 128 + tm * 8 + 4]);
            a[0] = a0.x; a[1] = a0.y; a[2] = a0.z; a[3] = a0.w;
            a[4] = a1.x; a[5] = a1.y; a[6] = a1.z; a[7] = a1.w;
            float bb[NR];
#pragma unroll
            for (int r4 = 0; r4 < NR / 4; ++r4) {
                const float4 bv = *reinterpret_cast<const float4*>(&b_lds[kk * BS + tn * NR + r4 * 4]);
                bb[r4 * 4 + 0] = bv.x; bb[r4 * 4 + 1] = bv.y;
                bb[r4 * 4 + 2] = bv.z; bb[r4 * 4 + 3] = bv.w;
            }
#pragma unroll
            for (int i = 0; i < 8; ++i)
#pragma unroll
                for (int r = 0; r < NR; ++r)
                    acc[i][r] += a[i] * bb[r];
        }
        __syncthreads();
    }

    // ---- epilogue: add bias, store ----
#pragma unroll
    for (int i = 0; i < 8; ++i) {
        const int m = m0 + tm * 8 + i;
        float* so = syn + (size_t)m * NT + tn * NR;
#pragma unroll
        for (int r = 0; r < NR; ++r) so[r] = acc[i][r] + bias[tn * NR + r];
    }
}

// ------------------------- FC scan: LIF over t, emit bits -------------------
// wave = (b, 64-neuron block); lane = neuron. Ballot -> SF[b][t][N/64] u64.
template <int N>
__global__ __launch_bounds__(256) void fc_scan_kernel(
    const float* __restrict__ syn,             // [chunk*50][N]
    unsigned long long* __restrict__ SF,       // [B][50][N/64]
    int b0)
{
    const int tid = threadIdx.x;
    const int wid = blockIdx.x * 4 + (tid >> 6);
    const int lane = tid & 63;
    constexpr int OB = N / 64;
    const int bl = wid / OB;
    const int ob = wid - bl * OB;
    const int o = ob * 64 + lane;

    float u = 0.f, v = 0.f, s = 0.f;
    for (int t = 0; t < 50; ++t) {
        const float sv = syn[((size_t)bl * 50 + t) * N + o];
        neuron_update(sv, u, v, s);
        const unsigned long long m = __ballot(s > 0.5f);
        if (lane == 0) SF[((size_t)(b0 + bl) * 50 + t) * OB + ob] = m;
    }
}

// ------------------------- fc4 GEMM (N=2, K=128) ----------------------------
__global__ __launch_bounds__(256) void fc4_gemm_kernel(
    const unsigned long long* __restrict__ SF3,  // [B][50][2] u64
    const float* __restrict__ W,                 // (2,128)
    const float* __restrict__ bias,              // (2,)
    float* __restrict__ syn4)                    // [B*50][2]
{
    const int m = blockIdx.x * 256 + threadIdx.x;   // 0..204799
    const unsigned long long w0 = SF3[(size_t)m * 2];
    const unsigned long long w1 = SF3[(size_t)m * 2 + 1];
    float a0 = 0.f, a1 = 0.f;
#pragma unroll
    for (int i = 0; i < 64; ++i) {
        const float bit = ((w0 >> i) & 1ULL) ? 1.f : 0.f;
        a0 += W[i] * bit;
        a1 += W[128 + i] * bit;
    }
#pragma unroll
    for (int i = 0; i < 64; ++i) {
        const float bit = ((w1 >> i) & 1ULL) ? 1.f : 0.f;
        a0 += W[64 + i] * bit;
        a1 += W[192 + i] * bit;
    }
    syn4[(size_t)m * 2]     = a0 + bias[0];
    syn4[(size_t)m * 2 + 1] = a1 + bias[1];
}

// ------------------------- fc4 scan + output --------------------------------
__global__ __launch_bounds__(64) void fc4_scan_kernel(
    const float* __restrict__ syn4, float* __restrict__ out)
{
    const int b = blockIdx.x * 64 + threadIdx.x;   // 0..4095
    float u0 = 0.f, v0 = 0.f, s0 = 0.f, acc0 = 0.f;
    float u1 = 0.f, v1 = 0.f, s1 = 0.f, acc1 = 0.f;
    for (int t = 0; t < 50; ++t) {
        const float x0 = syn4[((size_t)b * 50 + t) * 2];
        const float x1 = syn4[((size_t)b * 50 + t) * 2 + 1];
        neuron_update(x0, u0, v0, s0); acc0 += s0;
        neuron_update(x1, u1, v1, s1); acc1 += s1;
    }
    out[b * 2]     = acc0 / 50.0f;
    out[b * 2 + 1] = acc1 / 50.0f;
}

// ---------------------------------------------------------------------------
extern "C" void kernel_launch(void* const* d_in, const int* in_sizes, int n_in,
                              void* d_out, int out_size, void* d_ws, size_t ws_size,
                              hipStream_t stream) {
    (void)in_sizes; (void)n_in; (void)out_size;
    const float* normal = (const float*)d_in[0];   // (4096,6,50)
    const float* xscan  = (const float*)d_in[1];   // (4096,1,360,50)
    const float* w1  = (const float*)d_in[3];
    const float* b1  = (const float*)d_in[4];
    const float* w2  = (const float*)d_in[5];
    const float* b2  = (const float*)d_in[6];
    const float* w3  = (const float*)d_in[7];
    const float* b3  = (const float*)d_in[8];
    const float* fw1 = (const float*)d_in[9];
    const float* fb1 = (const float*)d_in[10];
    const float* fw2 = (const float*)d_in[11];
    const float* fb2 = (const float*)d_in[12];
    const float* fw3 = (const float*)d_in[13];
    const float* fb3 = (const float*)d_in[14];
    const float* fw4 = (const float*)d_in[15];
    const float* fb4 = (const float*)d_in[16];
    float* out = (float*)d_out;

    char* wp = (char*)d_ws;
    size_t off = 0;
    auto take = [&](size_t bytes) -> void* {
        void* p = wp + off;
        off += (bytes + 255) & ~(size_t)255;
        return p;
    };
    unsigned long long* S1  = (unsigned long long*)take((size_t)NB * 50 * 15 * 8);
    unsigned int*       S2  = (unsigned int*)take((size_t)NB * 50 * 15 * 4);
    unsigned int*       S3  = (unsigned int*)take((size_t)NB * 50 * 10 * 4);
    unsigned long long* SF1 = (unsigned long long*)take((size_t)NB * 50 * 4 * 8);
    unsigned long long* SF2 = (unsigned long long*)take((size_t)NB * 50 * 4 * 8);
    unsigned long long* SF3 = (unsigned long long*)take((size_t)NB * 50 * 2 * 8);
    float*              syn4 = (float*)take((size_t)NB * 50 * 2 * 4);

    // syn buffer: chunk the batch if workspace is small (deterministic in ws_size)
    int chunk = NB;
    while (chunk > 64 && off + (size_t)chunk * 50 * 256 * 4 > ws_size) chunk >>= 1;
    float* syn = (float*)take((size_t)chunk * 50 * 256 * 4);

    conv1_kernel<<<NB, 192, 0, stream>>>(xscan, w1, b1, S1);
    conv2_kernel<<<NB, 128, 0, stream>>>((const unsigned int*)S1, w2, b2, S2);
    conv3_kernel<<<NB, 64, 0, stream>>>(S2, w3, b3, S3);

    for (int b0 = 0; b0 < NB; b0 += chunk) {
        fc_gemm_kernel<7, 256, true><<<chunk * 50 / 128, 256, 0, stream>>>(
            S3, normal, fw1, fb1, syn, b0);
        fc_scan_kernel<256><<<chunk, 256, 0, stream>>>(syn, SF1, b0);
    }
    for (int b0 = 0; b0 < NB; b0 += chunk) {
        fc_gemm_kernel<8, 256, false><<<chunk * 50 / 128, 256, 0, stream>>>(
            (const unsigned int*)SF1, nullptr, fw2, fb2, syn, b0);
        fc_scan_kernel<256><<<chunk, 256, 0, stream>>>(syn, SF2, b0);
    }
    for (int b0 = 0; b0 < NB; b0 += chunk) {
        fc_gemm_kernel<8, 128, false><<<chunk * 50 / 128, 256, 0, stream>>>(
            (const unsigned int*)SF2, nullptr, fw3, fb3, syn, b0);
        fc_scan_kernel<128><<<chunk / 2, 256, 0, stream>>>(syn, SF3, b0);
    }
    fc4_gemm_kernel<<<NB * 50 / 256, 256, 0, stream>>>(SF3, fw4, fb4, syn4);
    fc4_scan_kernel<<<NB / 64, 64, 0, stream>>>(syn4, out);
}

// Round 4
// 1504.311 us; speedup vs baseline: 1.3015x; 1.3015x over previous
//
#include <hip/hip_runtime.h>
#include <cstdint>
#include <cstddef>

// ---------------------------------------------------------------------------
// ActorNetSpiking: layer-by-layer over time; spike trains bit-packed; FC
// layers as exact-order f32 VALU GEMM (k-sequential fmac chain per output,
// bit-identical to the validated round-0 numerics).
// ---------------------------------------------------------------------------

#define NB 4096

__device__ __forceinline__ void neuron_update(float syn, float& u, float& v, float& s) {
    u = u * 0.5f + syn;
    v = v * 0.75f * (1.0f - s) + u;
    s = (v > 0.5f) ? 1.0f : 0.0f;
}

// ------------------------- conv1: (B,1,360) -> (B,5,178) --------------------
__global__ __launch_bounds__(192) void conv1_kernel(
    const float* __restrict__ x, const float* __restrict__ w1,
    const float* __restrict__ b1, unsigned long long* __restrict__ S1)
{
    __shared__ float xl[9000];
    const int tid = threadIdx.x;
    const int b = blockIdx.x;
    const int j = tid;
    const int lbase = (j < 178) ? 2 * j : 354;

    float wr[25], br[5];
#pragma unroll
    for (int q = 0; q < 25; ++q) wr[q] = w1[q];
#pragma unroll
    for (int o = 0; o < 5; ++o) br[o] = b1[o];

    float u[5], v[5], s[5];
#pragma unroll
    for (int o = 0; o < 5; ++o) { u[o] = 0.f; v[o] = 0.f; s[o] = 0.f; }

    const float* xb = x + (size_t)b * 18000;
    for (int half = 0; half < 2; ++half) {
        const int t0 = half * 25;
        __syncthreads();
        for (int e = tid; e < 9000; e += 192)
            xl[e] = xb[(e / 25) * 50 + t0 + (e % 25)];
        __syncthreads();
        for (int dt = 0; dt < 25; ++dt) {
            const int t = t0 + dt;
            float xv[5];
#pragma unroll
            for (int k = 0; k < 5; ++k) xv[k] = xl[(lbase + k) * 25 + dt];
#pragma unroll
            for (int o = 0; o < 5; ++o) {
                float syn = 0.f;
#pragma unroll
                for (int k = 0; k < 5; ++k) syn += wr[o * 5 + k] * xv[k];
                syn += br[o];
                neuron_update(syn, u[o], v[o], s[o]);
                unsigned long long m = __ballot(j < 178 && s[o] > 0.5f);
                if ((tid & 63) == 0)
                    S1[(((size_t)b * 50 + t) * 5 + o) * 3 + (tid >> 6)] = m;
            }
        }
    }
}

// ------------------------- conv2: (B,5,178) -> (B,5,87) ---------------------
__global__ __launch_bounds__(128) void conv2_kernel(
    const unsigned int* __restrict__ S1, const float* __restrict__ w2,
    const float* __restrict__ b2, unsigned int* __restrict__ S2)
{
    __shared__ unsigned int s1l[1501];
    const int tid = threadIdx.x;
    const int b = blockIdx.x;

    float wr[125], br[5];
#pragma unroll
    for (int q = 0; q < 125; ++q) wr[q] = w2[q];
#pragma unroll
    for (int o = 0; o < 5; ++o) br[o] = b2[o];

    const unsigned int* src = S1 + (size_t)b * 1500;
    for (int e = tid; e < 1500; e += 128) s1l[e] = src[e];
    __syncthreads();

    const int p = (tid < 87) ? 2 * tid : 172;
    const int pw = p >> 5, ps = p & 31;

    float u[5], v[5], s[5];
#pragma unroll
    for (int o = 0; o < 5; ++o) { u[o] = 0.f; v[o] = 0.f; s[o] = 0.f; }

    for (int t = 0; t < 50; ++t) {
        float xv[25];
#pragma unroll
        for (int ci = 0; ci < 5; ++ci) {
            const int base = (t * 5 + ci) * 6 + pw;
            unsigned long long bits =
                ((((unsigned long long)s1l[base + 1]) << 32) | (unsigned long long)s1l[base]) >> ps;
#pragma unroll
            for (int k = 0; k < 5; ++k)
                xv[ci * 5 + k] = ((bits >> k) & 1ULL) ? 1.0f : 0.0f;
        }
#pragma unroll
        for (int o = 0; o < 5; ++o) {
            float syn = 0.f;
#pragma unroll
            for (int q = 0; q < 25; ++q) syn += wr[o * 25 + q] * xv[q];
            syn += br[o];
            neuron_update(syn, u[o], v[o], s[o]);
            unsigned long long m = __ballot(tid < 87 && s[o] > 0.5f);
            const size_t outb = (((size_t)b * 50 + t) * 5 + o) * 3;
            if (tid == 0) {
                S2[outb]     = (unsigned int)m;
                S2[outb + 1] = (unsigned int)(m >> 32);
            }
            if (tid == 64) S2[outb + 2] = (unsigned int)m;
        }
    }
}

// ------------------------- conv3: (B,5,87) -> packed 216-bit rows -----------
// Output S3[b][t][4 u64]: bits 0..209 = conv3 spikes (k = o*42+j),
// bits 210..215 = normal_spikes, rest 0.
__global__ __launch_bounds__(64) void conv3_kernel(
    const unsigned int* __restrict__ S2, const float* __restrict__ w3,
    const float* __restrict__ b3, const float* __restrict__ normal,
    unsigned long long* __restrict__ S3)
{
    __shared__ unsigned int s2l[751];
    const int tid = threadIdx.x;
    const int b = blockIdx.x;

    float wr[125], br[5];
#pragma unroll
    for (int q = 0; q < 125; ++q) wr[q] = w3[q];
#pragma unroll
    for (int o = 0; o < 5; ++o) br[o] = b3[o];

    const unsigned int* src = S2 + (size_t)b * 750;
    for (int e = tid; e < 750; e += 64) s2l[e] = src[e];
    __syncthreads();

    const int p = (tid < 42) ? 2 * tid : 82;
    const int pw = p >> 5, ps = p & 31;

    float u[5], v[5], s[5];
#pragma unroll
    for (int o = 0; o < 5; ++o) { u[o] = 0.f; v[o] = 0.f; s[o] = 0.f; }

    for (int t = 0; t < 50; ++t) {
        float xv[25];
#pragma unroll
        for (int ci = 0; ci < 5; ++ci) {
            const int base = (t * 5 + ci) * 3 + pw;
            unsigned long long bits =
                ((((unsigned long long)s2l[base + 1]) << 32) | (unsigned long long)s2l[base]) >> ps;
#pragma unroll
            for (int k = 0; k < 5; ++k)
                xv[ci * 5 + k] = ((bits >> k) & 1ULL) ? 1.0f : 0.0f;
        }
        unsigned long long m[5];
#pragma unroll
        for (int o = 0; o < 5; ++o) {
            float syn = 0.f;
#pragma unroll
            for (int q = 0; q < 25; ++q) syn += wr[o * 25 + q] * xv[q];
            syn += br[o];
            neuron_update(syn, u[o], v[o], s[o]);
            m[o] = __ballot(tid < 42 && s[o] > 0.5f);
        }
        const unsigned long long nm =
            __ballot(tid < 6 && normal[((size_t)b * 6 + tid) * 50 + t] > 0.5f);
        if (tid == 0) {
            unsigned long long r0 = m[0] | (m[1] << 42);
            unsigned long long r1 = (m[1] >> 22) | (m[2] << 20) | (m[3] << 62);
            unsigned long long r2 = (m[3] >> 2) | (m[4] << 40);
            unsigned long long r3 = (m[4] >> 24) | (nm << 18);
            unsigned long long* dst = S3 + ((size_t)b * 50 + t) * 4;
            dst[0] = r0; dst[1] = r1; dst[2] = r2; dst[3] = r3;
        }
    }
}

// ------------------------- exact-order VALU GEMM ----------------------------
// syn[m][n] = (sum_{k ascending} a[m][k]*W[n][k]) + bias[n], fmac chain with a
// single accumulator per output (bit-identical to validated round-0 order).
// Block: 256 thr, tile 256m x 128n; thread: 16m x 8n.
// A: bit rows (8 u32 per row) expanded to f32 in LDS with transposed-granule
// layout (conflict-free f4 reads). B: [kk][n] in LDS (conflict-free).
__global__ __launch_bounds__(256, 2) void exact_gemm_kernel(
    const uint32_t* __restrict__ bits,     // [Mglobal][8] u32
    const float* __restrict__ W,           // (Ntot, KREAL) row-major
    const float* __restrict__ bias,        // (Ntot,)
    float* __restrict__ syn,               // [Mchunk][Ntot]
    int Ntot, int KREAL, int KT, int row0)
{
    __shared__ __align__(16) float a_lds[32 * 256];   // 32 KB, [kk][perm-word]
    __shared__ __align__(16) float b_lds[32 * 128];   // 16 KB, [kk][n]

    const int tid = threadIdx.x;
    const int m0 = blockIdx.x * 256;
    const int nbase = blockIdx.y * 128;
    const int tm = tid & 15, tn = tid >> 4;           // tn 0..15

    // A staging: thread owns row m = tid; granule mq=tid>>2 stored at
    // p = ((mq&3)<<4)|(mq>>2) so reads (p = iq*16+tm) hit 16 consecutive
    // granules -> conflict-free-ish (2-way aliasing, free).
    const uint32_t* myBits = bits + (size_t)(row0 + m0 + tid) * 8;
    const int awBase = ((((tid >> 2) & 3) << 4) | (tid >> 4)) * 4 + (tid & 3);

    // B staging: thread covers n = tid&127, k-subrange of 16
    const int bn = tid & 127;
    const int bk0 = (tid >> 7) * 16;
    const float* wRow = W + (size_t)(nbase + bn) * KREAL;

    float acc[16][8];
#pragma unroll
    for (int j = 0; j < 16; ++j)
#pragma unroll
        for (int r = 0; r < 8; ++r) acc[j][r] = 0.f;

    for (int kt = 0; kt < KT; ++kt) {
        const int k0 = kt * 32;

        // issue global loads early (hide under previous tile's tail + barrier)
        const uint32_t wbits = myBits[kt];
        float4 bq[4];
#pragma unroll
        for (int i = 0; i < 4; ++i) {
            const int k = k0 + bk0 + i * 4;
            if (k + 3 < KREAL) {
                bq[i] = *reinterpret_cast<const float4*>(&wRow[k]);
            } else {
                float x = 0.f, y = 0.f, z = 0.f, w = 0.f;
                if (k     < KREAL) x = wRow[k];
                if (k + 1 < KREAL) y = wRow[k + 1];
                if (k + 2 < KREAL) z = wRow[k + 2];
                if (k + 3 < KREAL) w = wRow[k + 3];
                bq[i] = make_float4(x, y, z, w);
            }
        }

        __syncthreads();   // previous tile's readers done

#pragma unroll
        for (int kk = 0; kk < 32; ++kk)
            a_lds[kk * 256 + awBase] = ((wbits >> kk) & 1u) ? 1.0f : 0.0f;
        // B stores: [kk][n] scalar writes; threads bn=0..127 x bk0 x i x c
        // cover every slot exactly once (no zero-fill -- all k<KREAL slots
        // written with real values, k>=KREAL slots written with 0 via bq).
#pragma unroll
        for (int i = 0; i < 4; ++i) {
            b_lds[(bk0 + i * 4 + 0) * 128 + bn] = bq[i].x;
            b_lds[(bk0 + i * 4 + 1) * 128 + bn] = bq[i].y;
            b_lds[(bk0 + i * 4 + 2) * 128 + bn] = bq[i].z;
            b_lds[(bk0 + i * 4 + 3) * 128 + bn] = bq[i].w;
        }
        __syncthreads();

#pragma unroll 2
        for (int kk = 0; kk < 32; ++kk) {
            float a[16];
#pragma unroll
            for (int iq = 0; iq < 4; ++iq) {
                const float4 av = *reinterpret_cast<const float4*>(
                    &a_lds[kk * 256 + (iq * 16 + tm) * 4]);
                a[iq * 4 + 0] = av.x; a[iq * 4 + 1] = av.y;
                a[iq * 4 + 2] = av.z; a[iq * 4 + 3] = av.w;
            }
            float bf[8];
            const float4 b0 = *reinterpret_cast<const float4*>(
                &b_lds[kk * 128 + tn * 8]);
            const float4 b1 = *reinterpret_cast<const float4*>(
                &b_lds[kk * 128 + tn * 8 + 4]);
            bf[0] = b0.x; bf[1] = b0.y; bf[2] = b0.z; bf[3] = b0.w;
            bf[4] = b1.x; bf[5] = b1.y; bf[6] = b1.z; bf[7] = b1.w;
#pragma unroll
            for (int j = 0; j < 16; ++j)
#pragma unroll
                for (int r = 0; r < 8; ++r)
                    acc[j][r] += a[j] * bf[r];
        }
    }

    // epilogue: single bias add (same op order as validated baseline)
#pragma unroll
    for (int j = 0; j < 16; ++j) {
        const int m = m0 + tm * 16 + j;
        float* so = syn + (size_t)m * Ntot + nbase + tn * 8;
        float4 o0, o1;
        o0.x = acc[j][0] + bias[nbase + tn * 8 + 0];
        o0.y = acc[j][1] + bias[nbase + tn * 8 + 1];
        o0.z = acc[j][2] + bias[nbase + tn * 8 + 2];
        o0.w = acc[j][3] + bias[nbase + tn * 8 + 3];
        o1.x = acc[j][4] + bias[nbase + tn * 8 + 4];
        o1.y = acc[j][5] + bias[nbase + tn * 8 + 5];
        o1.z = acc[j][6] + bias[nbase + tn * 8 + 6];
        o1.w = acc[j][7] + bias[nbase + tn * 8 + 7];
        *reinterpret_cast<float4*>(so) = o0;
        *reinterpret_cast<float4*>(so + 4) = o1;
    }
}

// ------------------------- FC scan: LIF over t, emit bit rows ---------------
template <int N>
__global__ __launch_bounds__(256) void fc_scan_kernel(
    const float* __restrict__ syn, unsigned long long* __restrict__ SF, int b0)
{
    const int tid = threadIdx.x;
    const int wid = blockIdx.x * 4 + (tid >> 6);
    const int lane = tid & 63;
    constexpr int OB = N / 64;
    const int bl = wid / OB;
    const int ob = wid - bl * OB;
    const int o = ob * 64 + lane;

    float u = 0.f, v = 0.f, s = 0.f;
    for (int t = 0; t < 50; ++t) {
        const float sv = syn[((size_t)bl * 50 + t) * N + o];
        neuron_update(sv, u, v, s);
        const unsigned long long m = __ballot(s > 0.5f);
        if (lane == 0) SF[((size_t)(b0 + bl) * 50 + t) * OB + ob] = m;
    }
}

// ------------------------- fc4 GEMM (N=2, K=128) ----------------------------
__global__ __launch_bounds__(256) void fc4_gemm_kernel(
    const unsigned long long* __restrict__ SF3, const float* __restrict__ W,
    const float* __restrict__ bias, float* __restrict__ syn4)
{
    const int m = blockIdx.x * 256 + threadIdx.x;
    const unsigned long long w0 = SF3[(size_t)m * 2];
    const unsigned long long w1 = SF3[(size_t)m * 2 + 1];
    float a0 = 0.f, a1 = 0.f;
#pragma unroll
    for (int i = 0; i < 64; ++i) {
        const float bit = ((w0 >> i) & 1ULL) ? 1.f : 0.f;
        a0 += W[i] * bit;
        a1 += W[128 + i] * bit;
    }
#pragma unroll
    for (int i = 0; i < 64; ++i) {
        const float bit = ((w1 >> i) & 1ULL) ? 1.f : 0.f;
        a0 += W[64 + i] * bit;
        a1 += W[192 + i] * bit;
    }
    syn4[(size_t)m * 2]     = a0 + bias[0];
    syn4[(size_t)m * 2 + 1] = a1 + bias[1];
}

__global__ __launch_bounds__(64) void fc4_scan_kernel(
    const float* __restrict__ syn4, float* __restrict__ out)
{
    const int b = blockIdx.x * 64 + threadIdx.x;
    float u0 = 0.f, v0 = 0.f, s0 = 0.f, acc0 = 0.f;
    float u1 = 0.f, v1 = 0.f, s1 = 0.f, acc1 = 0.f;
    for (int t = 0; t < 50; ++t) {
        const float x0 = syn4[((size_t)b * 50 + t) * 2];
        const float x1 = syn4[((size_t)b * 50 + t) * 2 + 1];
        neuron_update(x0, u0, v0, s0); acc0 += s0;
        neuron_update(x1, u1, v1, s1); acc1 += s1;
    }
    out[b * 2]     = acc0 / 50.0f;
    out[b * 2 + 1] = acc1 / 50.0f;
}

// ---------------------------------------------------------------------------
extern "C" void kernel_launch(void* const* d_in, const int* in_sizes, int n_in,
                              void* d_out, int out_size, void* d_ws, size_t ws_size,
                              hipStream_t stream) {
    (void)in_sizes; (void)n_in; (void)out_size;
    const float* normal = (const float*)d_in[0];
    const float* xscan  = (const float*)d_in[1];
    const float* w1  = (const float*)d_in[3];
    const float* b1  = (const float*)d_in[4];
    const float* w2  = (const float*)d_in[5];
    const float* b2  = (const float*)d_in[6];
    const float* w3  = (const float*)d_in[7];
    const float* b3  = (const float*)d_in[8];
    const float* fw1 = (const float*)d_in[9];
    const float* fb1 = (const float*)d_in[10];
    const float* fw2 = (const float*)d_in[11];
    const float* fb2 = (const float*)d_in[12];
    const float* fw3 = (const float*)d_in[13];
    const float* fb3 = (const float*)d_in[14];
    const float* fw4 = (const float*)d_in[15];
    const float* fb4 = (const float*)d_in[16];
    float* out = (float*)d_out;

    char* wp = (char*)d_ws;
    size_t off = 0;
    auto take = [&](size_t bytes) -> void* {
        void* p = wp + off;
        off += (bytes + 255) & ~(size_t)255;
        return p;
    };
    unsigned long long* S1  = (unsigned long long*)take((size_t)NB * 50 * 15 * 8);
    unsigned int*       S2  = (unsigned int*)take((size_t)NB * 50 * 15 * 4);
    unsigned long long* S3  = (unsigned long long*)take((size_t)NB * 50 * 4 * 8);
    unsigned long long* SF1 = (unsigned long long*)take((size_t)NB * 50 * 4 * 8);
    unsigned long long* SF2 = (unsigned long long*)take((size_t)NB * 50 * 4 * 8);
    unsigned long long* SF3 = (unsigned long long*)take((size_t)NB * 50 * 2 * 8);
    float*              syn4 = (float*)take((size_t)NB * 50 * 2 * 4);

    int chunk = NB;
    while (chunk > 128 && off + (size_t)chunk * 50 * 256 * 4 > ws_size) chunk >>= 1;
    float* syn = (float*)take((size_t)chunk * 50 * 256 * 4);

    conv1_kernel<<<NB, 192, 0, stream>>>(xscan, w1, b1, S1);
    conv2_kernel<<<NB, 128, 0, stream>>>((const unsigned int*)S1, w2, b2, S2);
    conv3_kernel<<<NB, 64, 0, stream>>>(S2, w3, b3, normal, S3);

    for (int b0 = 0; b0 < NB; b0 += chunk) {
        exact_gemm_kernel<<<dim3(chunk * 50 / 256, 2), 256, 0, stream>>>(
            (const uint32_t*)S3, fw1, fb1, syn, 256, 216, 7, b0 * 50);
        fc_scan_kernel<256><<<chunk, 256, 0, stream>>>(syn, SF1, b0);
    }
    for (int b0 = 0; b0 < NB; b0 += chunk) {
        exact_gemm_kernel<<<dim3(chunk * 50 / 256, 2), 256, 0, stream>>>(
            (const uint32_t*)SF1, fw2, fb2, syn, 256, 256, 8, b0 * 50);
        fc_scan_kernel<256><<<chunk, 256, 0, stream>>>(syn, SF2, b0);
    }
    for (int b0 = 0; b0 < NB; b0 += chunk) {
        exact_gemm_kernel<<<dim3(chunk * 50 / 256, 1), 256, 0, stream>>>(
            (const uint32_t*)SF2, fw3, fb3, syn, 128, 256, 8, b0 * 50);
        fc_scan_kernel<128><<<chunk / 2, 256, 0, stream>>>(syn, SF3, b0);
    }
    fc4_gemm_kernel<<<NB * 50 / 256, 256, 0, stream>>>(SF3, fw4, fb4, syn4);
    fc4_scan_kernel<<<NB / 64, 64, 0, stream>>>(syn4, out);
}